// Round 12
// baseline (86.690 us; speedup 1.0000x reference)
//
#include <hip/hip_runtime.h>

// XCorrExt: B=32, S=160000, N=320, H=160, TAU=257, LAG_CUT=33
// out[b,f,tau-33] = 2*num/(e0 + e_tau + 1e-5), tau in [33,256]
// num[b,f,tau] = sum_n fr[n]*ext[tau+n]; fr[n] = xp[160f+n]
// ext[t] = xp[160f+t] (t<320) | xp[160f+t-160] (t>=320) | f=999,t>=320: x[t-320]
//
// R16 = R15 (86.3us) + shared-A fused loop.
// R15 proved time ~ DS instruction count (shared-B: -17 frags -> -4.7us).
// A has the same redundancy: frh = frg + 32*5 halves, so h's A-frag at
// step s IS g's frag at step s+5 -> one progression frg + off0 + 32t,
// t in [0,22): 22 unique b128 loads vs 34. The Toeplitz zeros differ per
// chain (g: off in [0,312]; h: off-160 in [0,312]) -> load once from
// clamped addr oc = clamp(off,0,472) (union range; always in-bounds and
// 16B-aligned), then per-chain cndmask-zero vs inline 0 (VALU, no DS).
// B window BW[u] loaded at t=u, used at t=u and t=u+5 (<=6 live under
// full unroll). Straddles (g@t=8, h@t=13) + f=999 tail = R15 logic.
// DS instrs/wave: 72 -> 60 inner (-17%); +~140 VALU/wave (absorbed).

typedef _Float16 f16;
typedef _Float16 h8 __attribute__((ext_vector_type(8)));
typedef _Float16 h4 __attribute__((ext_vector_type(4)));
typedef float    f4 __attribute__((ext_vector_type(4)));

#define S_LEN 160000
#define FN    1000
#define NF    8
#define BLOCK 256
#define USZ   1536              // staged signal floats: 160*(NF-1)+416

// smem byte offsets (all 16B-aligned)
#define ZPAD_OFF 0              // 16B zeros (legacy, unused by compute)
#define SE_OFF   16             // s_h: f16[1568] (zero pad [1536,1568))
#define SO_OFF   3152           // sO:  dword[784], dw j = halves (2j-1, 2j)
#define TH_OFF   6288           // T_h: f16[288] (zero pad [256,288))
#define TO_OFF   6864           // TO:  dword[144]
#define BRE_OFF  7440           // brE: f16[8][32]  = ext[304..336) per frame
#define BRO_OFF  7952           // brO: dword[8][16], dw j = ext halves (303+2j, 304+2j)
#define CSG_OFF  8464           // csg: float[1552] (excl. prefix of s^2)
#define CST_OFF  14672          // csT: float[260]
#define TOT_OFF  15712          // tot: float[260] (256 + wave sums)
#define SMEM_SZ  16752

__global__ __launch_bounds__(BLOCK)
void xcorr_kernel(const float* __restrict__ x, float* __restrict__ out) {
    __shared__ __align__(16) unsigned char smem[SMEM_SZ];
    f16*      s_h  = (f16*)(smem + SE_OFF);
    unsigned* sOd  = (unsigned*)(smem + SO_OFF);
    f16*      T_h  = (f16*)(smem + TH_OFF);
    unsigned* TOd  = (unsigned*)(smem + TO_OFF);
    f16*      brE  = (f16*)(smem + BRE_OFF);
    unsigned* brOd = (unsigned*)(smem + BRO_OFF);
    float*    csg  = (float*)(smem + CSG_OFF);
    float*    csT  = (float*)(smem + CST_OFF);
    float*    tot  = (float*)(smem + TOT_OFF);

    const int tid   = threadIdx.x;
    const int b     = blockIdx.y;
    const int fbase = blockIdx.x * NF;
    const long bOff = (long)b * S_LEN;
    const int gbase = fbase * 160;
    const bool lastBlk = (fbase + NF >= FN);

    // ---------------- P1: stage s_h (f16) + raw squares into csg --------------
    for (int i = 4*tid; i < USZ; i += 4*BLOCK) {
        const int gx = gbase + i;
        float v0, v1, v2, v3;
        if (gx + 3 < S_LEN) {
            const float4 v = *(const float4*)&x[bOff + gx];
            v0 = v.x; v1 = v.y; v2 = v.z; v3 = v.w;
        } else {
            v0 = (gx+0 < S_LEN) ? x[bOff+gx+0] : 0.f;
            v1 = (gx+1 < S_LEN) ? x[bOff+gx+1] : 0.f;
            v2 = (gx+2 < S_LEN) ? x[bOff+gx+2] : 0.f;
            v3 = (gx+3 < S_LEN) ? x[bOff+gx+3] : 0.f;
        }
        h4 hv; hv[0]=(f16)v0; hv[1]=(f16)v1; hv[2]=(f16)v2; hv[3]=(f16)v3;
        *(h4*)&s_h[i] = hv;
        f4 sq; sq[0]=v0*v0; sq[1]=v1*v1; sq[2]=v2*v2; sq[3]=v3*v3;
        *(f4*)&csg[i] = sq;
    }
    if (tid < 8) {                       // zero pad halves [1536,1568)
        h4 z; z[0]=(f16)0.f; z[1]=(f16)0.f; z[2]=(f16)0.f; z[3]=(f16)0.f;
        *(h4*)&s_h[1536 + 4*tid] = z;
    }
    if (tid < 16) csg[1536 + tid] = 0.f;
    if (tid == 0) { uint4 z; z.x=z.y=z.z=z.w=0u; *(uint4*)(smem + ZPAD_OFF) = z; }
    if (lastBlk) {
        for (int j = tid; j < 288; j += BLOCK) {
            const float tv = (j < 256) ? x[bOff + j] : 0.f;
            T_h[j] = (f16)tv;
            if (j < 260) csT[j] = tv * tv;
        }
    }
    __syncthreads();

    // ---------------- P2: build sO (+TO) + bridge; csg local prefix -----------
    {
        const unsigned* sEd = (const unsigned*)s_h;     // 784 dwords
        for (int idx = tid; idx < 196; idx += BLOCK) {
            uint4 lo4;
            if (idx) lo4 = *(const uint4*)(sEd + 4*idx - 4);
            else     { lo4.x=lo4.y=lo4.z=0u; lo4.w=0u; }
            const uint4 hi4 = *(const uint4*)(sEd + 4*idx);
            uint4 o;
            o.x = __builtin_amdgcn_alignbit(hi4.x, lo4.w, 16);
            o.y = __builtin_amdgcn_alignbit(hi4.y, hi4.x, 16);
            o.z = __builtin_amdgcn_alignbit(hi4.z, hi4.y, 16);
            o.w = __builtin_amdgcn_alignbit(hi4.w, hi4.z, 16);
            *(uint4*)(sOd + 4*idx) = o;
        }
        if (lastBlk) {                   // TO: 144 dwords
            const unsigned* Td = (const unsigned*)T_h;
            for (int idx = tid; idx < 36; idx += BLOCK) {
                uint4 lo4;
                if (idx) lo4 = *(const uint4*)(Td + 4*idx - 4);
                else     { lo4.x=lo4.y=lo4.z=0u; lo4.w=0u; }
                const uint4 hi4 = *(const uint4*)(Td + 4*idx);
                uint4 o;
                o.x = __builtin_amdgcn_alignbit(hi4.x, lo4.w, 16);
                o.y = __builtin_amdgcn_alignbit(hi4.y, hi4.x, 16);
                o.z = __builtin_amdgcn_alignbit(hi4.z, hi4.y, 16);
                o.w = __builtin_amdgcn_alignbit(hi4.w, hi4.z, 16);
                *(uint4*)(TOd + 4*idx) = o;
            }
        }
        // bridge: ext[304..336) per frame (contiguous across the t=320 fold)
        {
            const int fi = tid >> 5, j = tid & 31;      // 256 threads exactly
            const int t = 304 + j;
            const bool lastF = lastBlk && (fbase + fi == FN-1);
            f16 v;
            if (t < 320)      v = s_h[160*fi + t];
            else if (lastF)   v = T_h[t - 320];
            else              v = s_h[160*fi + t - 160];
            brE[32*fi + j] = v;
        }
        if (tid < NF*16) {                              // 128 threads
            const int fi = tid >> 4, j = tid & 15;
            const int tl = 303 + 2*j, th = 304 + 2*j;
            const bool lastF = lastBlk && (fbase + fi == FN-1);
            const f16 lo = (tl < 320) ? s_h[160*fi + tl]
                          : (lastF ? T_h[tl-320] : s_h[160*fi + tl - 160]);
            const f16 hi = (th < 320) ? s_h[160*fi + th]
                          : (lastF ? T_h[th-320] : s_h[160*fi + th - 160]);
            union { struct { f16 a, c; } h; unsigned u; } pk;
            pk.h.a = lo; pk.h.c = hi;
            brOd[16*fi + j] = pk.u;
        }
    }
    float p[7]; float mytot = 0.f;
    {
        const int t0 = 7*tid;
#pragma unroll
        for (int e = 0; e < 7; ++e) {
            const float r = (t0+e < 1552) ? csg[t0+e] : 0.f;
            p[e] = mytot;                       // exclusive within thread
            mytot += r;
        }
        tot[tid] = mytot;
    }
    __syncthreads();

    // ---------------- P3: all-wave scan (wave-local shfl + wave totals) -------
    const int lane = tid & 63;
    const int wv   = tid >> 6;
    {
        const float v = tot[tid];
        float sc = v;
#pragma unroll
        for (int d = 1; d < 64; d <<= 1) {
            const float o = __shfl_up(sc, d);
            sc += (lane >= d) ? o : 0.f;
        }
        tot[tid] = sc - v;                      // exclusive within wave
        if (lane == 63) tot[256 + wv] = sc;     // wave total
        if (lastBlk && wv == 0) {               // exclusive scan of csT (260)
            float r[5]; float mt = 0.f;
#pragma unroll
            for (int e = 0; e < 5; ++e) {
                const int j = 5*lane + e;
                const float rv = (j < 260) ? csT[j] : 0.f;
                r[e] = mt; mt += rv;
            }
            float sc2 = mt;
#pragma unroll
            for (int d = 1; d < 64; d <<= 1) {
                const float o = __shfl_up(sc2, d);
                sc2 += (lane >= d) ? o : 0.f;
            }
            const float b2 = sc2 - mt;
#pragma unroll
            for (int e = 0; e < 5; ++e) {
                const int j = 5*lane + e;
                if (j < 260) csT[j] = b2 + r[e];
            }
        }
    }
    __syncthreads();

    // ---------------- P4: apply csg bases (exclusive prefix complete) ---------
    {
        const float w1 = tot[256], w2 = tot[257], w3 = tot[258];
        const float wbase = ((wv > 0) ? w1 : 0.f) + ((wv > 1) ? w2 : 0.f)
                          + ((wv > 2) ? w3 : 0.f);
        const float base = wbase + tot[tid];
        const int t0 = 7*tid;
#pragma unroll
        for (int e = 0; e < 7; ++e)
            if (t0+e < 1552) csg[t0+e] = base + p[e];
    }
    __syncthreads();

    // ---------------- compute: wave wv -> frames g=2wv, h=g+1 -----------------
    const int col  = lane & 15;          // A-row t1-lane, B-col t0, C-col
    const int q    = lane >> 4;          // k-group; C-row = 4q+v
    const int off0 = 8*q - 16*col;       // A: off = j - 16*row, j = 32s+8q
    const int tb0  = 33 + col + 8*q;     // B: half index base into ext, [33,72]
    const int pc   = tb0 & 1;
    const unsigned* bbS = pc ? sOd : (const unsigned*)s_h;
    const unsigned* bbT = pc ? TOd : (const unsigned*)T_h;

    const int g = 2*wv, h = g + 1;
    const int fg = fbase + g, fh = fbase + h;
    const bool isLastH = (fh == FN-1);   // only the odd frame can be 999
    const f16* frg = s_h + 160*g;
    const f16* frh = s_h + 160*h;
    const int j0 = (tb0 + pc) >> 1;
    const unsigned* pS  = bbS + 80*g + j0;   // shared B base: frag(u) = pS+16u
    const unsigned* pTB = bbT + ((tb0 - 320 + pc) >> 1);   // deref'd only if isLastH
    // straddle (s=8) pointers, per R12: frag read at p8 + 128
    const unsigned* brBg = pc ? (brOd + 16*g) : ((const unsigned*)brE + 16*g);
    const unsigned* brBh = pc ? (brOd + 16*h) : ((const unsigned*)brE + 16*h);
    const unsigned* pBh  = isLastH ? pTB : pS;
    const unsigned* p8g  = (tb0 <= 56) ? pS
                         : ((tb0 <= 63) ? (brBg + ((tb0 - 48 + pc) >> 1) - 128)
                                        : (pS - 80));
    const unsigned* p8h  = (tb0 <= 56) ? (pS + 80)
                         : ((tb0 <= 63) ? (brBh + ((tb0 - 48 + pc) >> 1) - 128)
                                        : pBh);

    auto BLOAD = [&](const unsigned* bp, int o) -> h8 {
        union { unsigned u[4]; h8 hh; } B_;
        B_.u[0] = bp[o+0]; B_.u[1] = bp[o+1];   // scalar b32 only: 4B-safe,
        B_.u[2] = bp[o+2]; B_.u[3] = bp[o+3];   // compiler fuses to read2_b32
        return B_.hh;
    };

    f4 accg = {0.f, 0.f, 0.f, 0.f};
    f4 acch = {0.f, 0.f, 0.f, 0.f};
    h8 BW[17];                           // frag u: loaded t=u, used t=u, u+5
#pragma unroll
    for (int t = 0; t < 22; ++t) {
        if (t < 17) BW[t] = BLOAD(pS, 16*t);
        // shared A fragment: frg + off serves g (s=t) and h (s=t-5)
        const int off = off0 + 32*t;
        const int oc  = off < 0 ? 0 : (off > 472 ? 472 : off);  // union-range clamp
        union { unsigned u[4]; h8 hh; } Fv;
        Fv.hh = *(const h8*)(frg + oc);                         // aligned b128
        if (t < 17) {                    // g chain, s = t
            const bool cg = ((unsigned)off <= 312u);
            union { unsigned u[4]; h8 hh; } Ag;
            Ag.u[0] = cg ? Fv.u[0] : 0u; Ag.u[1] = cg ? Fv.u[1] : 0u;
            Ag.u[2] = cg ? Fv.u[2] : 0u; Ag.u[3] = cg ? Fv.u[3] : 0u;
            if (t < 8)
                accg = __builtin_amdgcn_mfma_f32_16x16x32_f16(Ag.hh, BW[t], accg, 0, 0, 0);
            else if (t == 8)
                accg = __builtin_amdgcn_mfma_f32_16x16x32_f16(Ag.hh, BLOAD(p8g, 128), accg, 0, 0, 0);
            else
                accg = __builtin_amdgcn_mfma_f32_16x16x32_f16(Ag.hh, BW[t-5], accg, 0, 0, 0);
        }
        if (t >= 5) {                    // h chain, s = t-5
            const bool ch = ((unsigned)(off - 160) <= 312u);
            union { unsigned u[4]; h8 hh; } Ah;
            Ah.u[0] = ch ? Fv.u[0] : 0u; Ah.u[1] = ch ? Fv.u[1] : 0u;
            Ah.u[2] = ch ? Fv.u[2] : 0u; Ah.u[3] = ch ? Fv.u[3] : 0u;
            if (t <= 12)
                acch = __builtin_amdgcn_mfma_f32_16x16x32_f16(Ah.hh, BW[t], acch, 0, 0, 0);
            else if (t == 13)
                acch = __builtin_amdgcn_mfma_f32_16x16x32_f16(Ah.hh, BLOAD(p8h, 128), acch, 0, 0, 0);
            else if (!isLastH)           // wave-uniform guard
                acch = __builtin_amdgcn_mfma_f32_16x16x32_f16(Ah.hh, BW[t-5], acch, 0, 0, 0);
        }
    }
    if (isLastH) {                       // frame 999 regionB reads T (rare wave)
#pragma unroll
        for (int s = 9; s < 17; ++s) {
            const int off = off0 + 32*s + 160;               // frh frag = frg+off
            const int oc  = off < 160 ? 160 : (off > 472 ? 472 : off);
            const bool ch = (off == oc);
            union { unsigned u[4]; h8 hh; } Fv, Ah;
            Fv.hh = *(const h8*)(frg + oc);
            Ah.u[0] = ch ? Fv.u[0] : 0u; Ah.u[1] = ch ? Fv.u[1] : 0u;
            Ah.u[2] = ch ? Fv.u[2] : 0u; Ah.u[3] = ch ? Fv.u[3] : 0u;
            acch = __builtin_amdgcn_mfma_f32_16x16x32_f16(Ah.hh, BLOAD(pTB, 16*s), acch, 0, 0, 0);
        }
    }

    // ---------------- epilogue: energies from exact-fp32 prefix sums ----------
    {   // frame g (even fi: never the last frame)
        const int D = 160*g;
        const float c0   = csg[D];
        const float c160 = csg[D+160];
        const float c320 = csg[D+320];
        const float e0   = c320 - c0;
        float* op = &out[(long)(b*FN + fg) * 224];
#pragma unroll
        for (int v = 0; v < 4; ++v) {
            const int t1 = 4*q + v;
            if (t1 <= 13) {
                const int tau = 33 + 16*t1 + col;
                const float et = c320 - csg[D+tau] - c160 + csg[D+160+tau];
                const float den = e0 + et + 1e-5f;
                op[tau - 33] = 2.f * accg[v] * __builtin_amdgcn_rcpf(den);
            }
        }
    }
    {   // frame h
        const int D = 160*h;
        const float c0   = csg[D];
        const float c160 = csg[D+160];
        const float c320 = csg[D+320];
        const float e0   = c320 - c0;
        float* op = &out[(long)(b*FN + fh) * 224];
#pragma unroll
        for (int v = 0; v < 4; ++v) {
            const int t1 = 4*q + v;
            if (t1 <= 13) {
                const int tau = 33 + 16*t1 + col;
                const float et = isLastH
                    ? (c320 - csg[D+tau] + csT[tau])
                    : (c320 - csg[D+tau] - c160 + csg[D+160+tau]);
                const float den = e0 + et + 1e-5f;
                op[tau - 33] = 2.f * acch[v] * __builtin_amdgcn_rcpf(den);
            }
        }
    }
}

extern "C" void kernel_launch(void* const* d_in, const int* in_sizes, int n_in,
                              void* d_out, int out_size, void* d_ws, size_t ws_size,
                              hipStream_t stream) {
    const float* x = (const float*)d_in[0];
    float* out = (float*)d_out;
    dim3 grid(FN / NF, 32);              // (125, 32) = 4000 blocks
    dim3 block(BLOCK);
    hipLaunchKernelGGL(xcorr_kernel, grid, block, 0, stream, x, out);
}